// Round 11
// baseline (271.377 us; speedup 1.0000x reference)
//
#include <hip/hip_runtime.h>

typedef __attribute__((ext_vector_type(8))) short bf16x8;     // 8 bf16 in 4 VGPRs
typedef __attribute__((ext_vector_type(4))) short bf16x4;     // 4 bf16 in 2 VGPRs
typedef __attribute__((ext_vector_type(8))) unsigned short u16x8;
typedef __attribute__((ext_vector_type(4))) float f32x4;

__device__ __forceinline__ unsigned short f2b(float f) {      // f32 -> bf16 RNE
  unsigned int u = __builtin_bit_cast(unsigned int, f);
  u += 0x7FFFu + ((u >> 16) & 1u);
  return (unsigned short)(u >> 16);
}
__device__ __forceinline__ float b2f(unsigned short h) {
  return __builtin_bit_cast(float, ((unsigned int)h) << 16);
}

__device__ __forceinline__ f32x4 mfma16x16x16(bf16x4 a, bf16x4 b, f32x4 c) {
#if __has_builtin(__builtin_amdgcn_mfma_f32_16x16x16bf16_1k)
  return __builtin_amdgcn_mfma_f32_16x16x16bf16_1k(a, b, c, 0, 0, 0);
#else
  asm volatile("v_mfma_f32_16x16x16_bf16 %0, %1, %2, %0" : "+v"(c) : "v"(a), "v"(b));
  return c;
#endif
}

#define AS1(p) (const __attribute__((address_space(1))) void*)(p)
#define AS3(p) (__attribute__((address_space(3))) void*)(p)

// ---------------- merged f32 -> bf16 convert (5 segments) ----------------
__device__ __forceinline__ void cvt8(const float* __restrict__ in,
                                     unsigned short* __restrict__ out,
                                     int i, float scale) {
  const float4* p = (const float4*)in + (size_t)i * 2;
  float4 a = p[0], b = p[1];
  u16x8 r;
  r[0] = f2b(a.x * scale); r[1] = f2b(a.y * scale);
  r[2] = f2b(a.z * scale); r[3] = f2b(a.w * scale);
  r[4] = f2b(b.x * scale); r[5] = f2b(b.y * scale);
  r[6] = f2b(b.z * scale); r[7] = f2b(b.w * scale);
  *((u16x8*)out + i) = r;
}

__global__ __launch_bounds__(256) void k_cvt_all(
    const float* __restrict__ x,  const float* __restrict__ Wq,
    const float* __restrict__ Wk, const float* __restrict__ Wv,
    const float* __restrict__ Wo, unsigned short* __restrict__ xb,
    unsigned short* __restrict__ wqkv, unsigned short* __restrict__ Wob,
    float sc) {
  int bid = blockIdx.x;                      // 9216 blocks total, 2048 elems each
  int tid = threadIdx.x;
  if (bid < 4096)      cvt8(x,  xb,             (bid        ) * 256 + tid, 1.f);
  else if (bid < 6144) cvt8(Wq, wqkv,           (bid - 4096) * 256 + tid, sc);
  else if (bid < 6656) cvt8(Wk, wqkv + 4194304, (bid - 6144) * 256 + tid, 1.f);
  else if (bid < 7168) cvt8(Wv, wqkv + 5242880, (bid - 6656) * 256 + tid, 1.f);
  else                 cvt8(Wo, Wob,            (bid - 7168) * 256 + tid, 1.f);
}

// ---------------- merged RoPE (q/k cols) + V transpose ----------------
__global__ __launch_bounds__(256) void k_post(unsigned short* __restrict__ qkv,
                                              const float* __restrict__ cosb,
                                              const float* __restrict__ sinb,
                                              unsigned short* __restrict__ vT) {
  __shared__ unsigned short tile[64][72];
  const int bid = blockIdx.x, t = threadIdx.x;
  if (bid < 2560) {
    int tid = bid * 256 + t;                 // 4096*20*8 = 655360
    int oct = tid & 7;
    int hd  = (tid >> 3) % 20;
    int s   = (tid >> 3) / 20;
    unsigned short* p1 = qkv + (size_t)s * 3072 + hd * 128 + oct * 8;
    unsigned short* p2 = p1 + 64;
    u16x8 a = *(const u16x8*)p1;
    u16x8 b = *(const u16x8*)p2;
    const float4* cp = (const float4*)(cosb + (size_t)s * 128 + oct * 8);
    const float4* sp = (const float4*)(sinb + (size_t)s * 128 + oct * 8);
    float4 c0 = cp[0], c1 = cp[1], s0 = sp[0], s1 = sp[1];
    float cs[8] = {c0.x,c0.y,c0.z,c0.w,c1.x,c1.y,c1.z,c1.w};
    float sn[8] = {s0.x,s0.y,s0.z,s0.w,s1.x,s1.y,s1.z,s1.w};
    u16x8 ra, rb;
#pragma unroll
    for (int j = 0; j < 8; ++j) {
      float av = b2f(a[j]), bv = b2f(b[j]);
      ra[j] = f2b(av * cs[j] - bv * sn[j]);
      rb[j] = f2b(bv * cs[j] + av * sn[j]);
    }
    *(u16x8*)p1 = ra;
    *(u16x8*)p2 = rb;
  } else {
    int idx = bid - 2560;                    // 512 tiles
    int bs = idx >> 3, bc = idx & 7;
#pragma unroll
    for (int i = 0; i < 2; ++i) {
      int c8 = t + 256 * i;                  // 0..511
      int row = c8 >> 3, cb = c8 & 7;
      u16x8 v = *(const u16x8*)(qkv + (size_t)(bs * 64 + row) * 3072 + 2560 + bc * 64 + cb * 8);
#pragma unroll
      for (int j = 0; j < 8; ++j) tile[row][cb * 8 + j] = v[j];
    }
    __syncthreads();
#pragma unroll
    for (int i = 0; i < 2; ++i) {
      int c8 = t + 256 * i;
      int crow = c8 >> 3, sb = c8 & 7;
      u16x8 v;
#pragma unroll
      for (int j = 0; j < 8; ++j) v[j] = tile[sb * 8 + j][crow];
      *(u16x8*)(vT + (size_t)(bc * 64 + crow) * 4096 + bs * 64 + sb * 8) = v;
    }
  }
}

// ---------------- GEMM C[M,N] = A[M,K] @ B[N,K]^T (bf16 in, bf16/f32 out) --
template <int OUTF32>
__global__ __launch_bounds__(256) void k_gemm_bt(
    const unsigned short* __restrict__ A, const unsigned short* __restrict__ B,
    void* __restrict__ C, int K, int lda, int ldb, int ldc) {
  __shared__ unsigned short As[128 * 64];
  __shared__ unsigned short Bs[128 * 64];
  const int t = threadIdx.x;
  const int lane = t & 63, w = t >> 6;
  const int wm = w >> 1, wn = w & 1;
  const int bn = blockIdx.x, bm = blockIdx.y;
  const unsigned short* Arow = A + (size_t)(bm * 128) * lda;
  const unsigned short* Brow = B + (size_t)(bn * 128) * ldb;

  f32x4 acc[4][4] = {};
  for (int kt = 0; kt < K; kt += 64) {
#pragma unroll
    for (int i = 0; i < 4; ++i) {
      int idx = i * 256 + t;
      int r = idx >> 3, blk = idx & 7;
      int sb = blk ^ (r & 7);
      __builtin_amdgcn_global_load_lds(AS1(Arow + (size_t)r * lda + kt + sb * 8),
                                       AS3(As + (i * 256 + w * 64) * 8), 16, 0, 0);
    }
#pragma unroll
    for (int i = 0; i < 4; ++i) {
      int idx = i * 256 + t;
      int r = idx >> 3, blk = idx & 7;
      int sb = blk ^ (r & 7);
      __builtin_amdgcn_global_load_lds(AS1(Brow + (size_t)r * ldb + kt + sb * 8),
                                       AS3(Bs + (i * 256 + w * 64) * 8), 16, 0, 0);
    }
    __syncthreads();
#pragma unroll
    for (int kk = 0; kk < 2; ++kk) {
      bf16x8 av[4], bv[4];
#pragma unroll
      for (int i = 0; i < 4; ++i) {
        int r = wm * 64 + i * 16 + (lane & 15);
        int off = (r * 128 + (kk * 32 + (lane >> 4) * 8) * 2) ^ ((r & 7) << 4);
        av[i] = *(const bf16x8*)((const char*)As + off);
      }
#pragma unroll
      for (int j = 0; j < 4; ++j) {
        int r = wn * 64 + j * 16 + (lane & 15);
        int off = (r * 128 + (kk * 32 + (lane >> 4) * 8) * 2) ^ ((r & 7) << 4);
        bv[j] = *(const bf16x8*)((const char*)Bs + off);
      }
#pragma unroll
      for (int i = 0; i < 4; ++i)
#pragma unroll
        for (int j = 0; j < 4; ++j)
          acc[i][j] = __builtin_amdgcn_mfma_f32_16x16x32_bf16(av[i], bv[j], acc[i][j], 0, 0, 0);
    }
    __syncthreads();
  }
#pragma unroll
  for (int i = 0; i < 4; ++i)
#pragma unroll
    for (int j = 0; j < 4; ++j)
#pragma unroll
      for (int r = 0; r < 4; ++r) {
        int m = bm * 128 + wm * 64 + i * 16 + (lane >> 4) * 4 + r;
        int n = bn * 128 + wn * 64 + j * 16 + (lane & 15);
        float v = acc[i][j][r];
        if (OUTF32) ((float*)C)[(size_t)m * ldc + n] = v;
        else        ((unsigned short*)C)[(size_t)m * ldc + n] = f2b(v);
      }
}

// ---------------- attention staging helpers (512-thread block) -------------
__device__ __forceinline__ void stage_k8(const unsigned short* __restrict__ qk,
                                         unsigned short* __restrict__ dst,
                                         int kt, int g, int t, int w) {
#pragma unroll
  for (int i = 0; i < 2; ++i) {   // K tile [64 keys][128 d], swz low 3 bits of col16
    int idx = i * 512 + t;        // 0..1023
    int r = idx >> 4, blk = idx & 15;
    int sb = (blk & 8) | ((blk ^ r) & 7);
    __builtin_amdgcn_global_load_lds(
        AS1(qk + (size_t)(kt * 64 + r) * 3072 + 2048 + g * 128 + sb * 8),
        AS3(dst + (i * 512 + w * 64) * 8), 16, 0, 0);
  }
}
__device__ __forceinline__ void stage_v8(const unsigned short* __restrict__ vT,
                                         unsigned short* __restrict__ dst,
                                         int kt, int g, int t, int w) {
#pragma unroll
  for (int i = 0; i < 2; ++i) {   // V^T tile [128 d][64 keys]
    int idx = i * 512 + t;
    int r = idx >> 3, blk = idx & 7;
    int sb = blk ^ (r & 7);
    __builtin_amdgcn_global_load_lds(
        AS1(vT + (size_t)(g * 128 + r) * 4096 + kt * 64 + sb * 8),
        AS3(dst + (i * 512 + w * 64) * 8), 16, 0, 0);
  }
}

// ---------------- fused causal GQA flash attention ----------------
// Dual-q-tile 512-thread block: waves 0-3 own qt=b, waves 4-7 own qt=63-b.
// Both wave-groups consume ONE shared K/V staging stream (staged once per kt
// -> 25% less stage traffic than per-group staging); group A skips compute
// (keeps barriers) once kt > b. Per-wave tile math identical to r10
// (2 heads of one KV group per wave, swapped QK^T, register P, dbuf K/V).
// Grid (32,8) = 256 blocks = 1 block/CU, 8 waves/CU from t=0.
__global__ __launch_bounds__(512, 1) void k_attn(const unsigned short* __restrict__ qk,
                                                 const unsigned short* __restrict__ vT,
                                                 unsigned short* __restrict__ ctx) {
  __shared__ unsigned short Ks[2][64 * 128];
  __shared__ unsigned short Vs[2][64 * 128];
  const int b = blockIdx.x;                  // 0..31
  const int hp = blockIdx.y;                 // head pair: heads 2hp, 2hp+1
  const int h0 = hp * 2, g = hp >> 1;        // same KV group for both heads
  const int t = threadIdx.x, lane = t & 63, w = t >> 6;   // w 0..7
  const int wq = w & 3;                      // row-group within the 64-row tile
  const int myqt = (w < 4) ? b : 63 - b;     // this wave-group's q tile
  const int kmax = 63 - b;                   // loop bound (>= both qt)
  const int l15 = lane & 15, lq = lane >> 4;
  const int qg = myqt * 64 + wq * 16 + l15;  // this lane's softmax q-row (global)

  bf16x8 aq0[4], aq1[4];          // Q fragments, both heads
  {
    const unsigned short* qb =
        qk + (size_t)(myqt * 64 + wq * 16 + l15) * 3072 + h0 * 128 + lq * 8;
#pragma unroll
    for (int sl = 0; sl < 4; ++sl) {
      aq0[sl] = *(const bf16x8*)(qb + sl * 32);
      aq1[sl] = *(const bf16x8*)(qb + 128 + sl * 32);
    }
  }
  f32x4 o0[8] = {}, o1[8] = {};
  float lsum0 = 0.f, lsum1 = 0.f;

  stage_k8(qk, Ks[0], 0, g, t, w);
  stage_v8(vT, Vs[0], 0, g, t, w);
  asm volatile("s_waitcnt vmcnt(0)" ::: "memory");
  __builtin_amdgcn_s_barrier();

  auto tile = [&](const unsigned short* Kb, const unsigned short* Vb,
                  int kt, bool maskT) {
    // ---- S^T = K @ Q^T for both heads (shared K read) ----
    f32x4 st0[4] = {}, st1[4] = {};
    __builtin_amdgcn_s_setprio(1);
#pragma unroll
    for (int sl = 0; sl < 4; ++sl)
#pragma unroll
      for (int nt = 0; nt < 4; ++nt) {
        int key = nt * 16 + l15;
        int off = (key * 256 + sl * 64 + lq * 16) ^ ((key & 7) << 4);
        bf16x8 bk = *(const bf16x8*)((const char*)Kb + off);
        st0[nt] = __builtin_amdgcn_mfma_f32_16x16x32_bf16(bk, aq0[sl], st0[nt], 0, 0, 0);
        st1[nt] = __builtin_amdgcn_mfma_f32_16x16x32_bf16(bk, aq1[sl], st1[nt], 0, 0, 0);
      }
    __builtin_amdgcn_s_setprio(0);

    // ---- streaming softmax, in-register (Q pre-scaled, no max) ----
    bf16x4 pa0[4], pa1[4];
#pragma unroll
    for (int nt = 0; nt < 4; ++nt)
#pragma unroll
      for (int r = 0; r < 4; ++r) {
        float p0 = __builtin_amdgcn_exp2f(st0[nt][r]);
        float p1 = __builtin_amdgcn_exp2f(st1[nt][r]);
        if (maskT) {
          int key = kt * 64 + nt * 16 + lq * 4 + r;
          if (key > qg) { p0 = 0.f; p1 = 0.f; }
        }
        lsum0 += p0; lsum1 += p1;
        unsigned int u0 = __builtin_bit_cast(unsigned int, p0) + 0x8000u;
        unsigned int u1 = __builtin_bit_cast(unsigned int, p1) + 0x8000u;
        pa0[nt][r] = (short)(u0 >> 16);
        pa1[nt][r] = (short)(u1 >> 16);
      }

    // ---- O += P @ V for both heads (shared V read) ----
    __builtin_amdgcn_s_setprio(1);
#pragma unroll
    for (int nt = 0; nt < 4; ++nt)
#pragma unroll
      for (int dt = 0; dt < 8; ++dt) {
        int d = dt * 16 + l15;
        int off = (d * 128 + nt * 32 + lq * 8) ^ ((d & 7) << 4);
        bf16x4 vv = *(const bf16x4*)((const char*)Vb + off);
        o0[dt] = mfma16x16x16(pa0[nt], vv, o0[dt]);
        o1[dt] = mfma16x16x16(pa1[nt], vv, o1[dt]);
      }
    __builtin_amdgcn_s_setprio(0);
  };

  for (int kt = 0; kt <= kmax; ++kt) {
    const int cur = kt & 1;
    if (kt < kmax) {                          // prefetch next tile (shared)
      stage_k8(qk, Ks[cur ^ 1], kt + 1, g, t, w);
      stage_v8(vT, Vs[cur ^ 1], kt + 1, g, t, w);
    }
    if (kt <= myqt)                           // group A skips once kt > b
      tile(Ks[cur], Vs[cur], kt, kt == myqt);
    asm volatile("s_waitcnt vmcnt(0)" ::: "memory");  // prefetch landed
    __builtin_amdgcn_s_barrier();
  }

  // ---- epilogue: row-sum reduce (4 lq-slices), normalize, store ----
  float f0 = lsum0, f1 = lsum1;
  f0 += __shfl_xor(f0, 16); f0 += __shfl_xor(f0, 32);
  f1 += __shfl_xor(f1, 16); f1 += __shfl_xor(f1, 32);
  float iq0[4], iq1[4];
#pragma unroll
  for (int r = 0; r < 4; ++r) {
    iq0[r] = 1.f / __shfl(f0, lq * 4 + r);
    iq1[r] = 1.f / __shfl(f1, lq * 4 + r);
  }
#pragma unroll
  for (int dt = 0; dt < 8; ++dt)
#pragma unroll
    for (int r = 0; r < 4; ++r) {
      int q = myqt * 64 + wq * 16 + lq * 4 + r;
      int c = h0 * 128 + dt * 16 + l15;
      ctx[(size_t)q * 2048 + c]       = f2b(o0[dt][r] * iq0[r]);
      ctx[(size_t)q * 2048 + c + 128] = f2b(o1[dt][r] * iq1[r]);
    }
}

// ---------------- host ----------------
extern "C" void kernel_launch(void* const* d_in, const int* in_sizes, int n_in,
                              void* d_out, int out_size, void* d_ws, size_t ws_size,
                              hipStream_t stream) {
  const float* x    = (const float*)d_in[0];
  const float* cosb = (const float*)d_in[2];
  const float* sinb = (const float*)d_in[3];
  const float* Wq   = (const float*)d_in[4];
  const float* Wk   = (const float*)d_in[5];
  const float* Wv   = (const float*)d_in[6];
  const float* Wo   = (const float*)d_in[7];

  char* p = (char*)d_ws;
  unsigned short* xb   = (unsigned short*)p; p += (size_t)8388608 * 2;   // x bf16
  unsigned short* wqkv = (unsigned short*)p; p += (size_t)6291456 * 2;   // [3072][2048]
  unsigned short* Wob  = (unsigned short*)p; p += (size_t)4194304 * 2;
  unsigned short* qkvb = (unsigned short*)p; p += (size_t)4096 * 3072 * 2;
  unsigned short* vTb  = (unsigned short*)p; p += (size_t)512 * 4096 * 2;
  unsigned short* ctx  = (unsigned short*)p; p += (size_t)4096 * 2048 * 2;
  if (ws_size < (size_t)(p - (char*)d_ws)) return;

  const float SC = 0.12751741f;   // (1/sqrt(128)) * log2(e), folded into Wq

  k_cvt_all<<<9216, 256, 0, stream>>>(x, Wq, Wk, Wv, Wo, xb, wqkv, Wob, SC);

  // qkv = x @ [Wq;Wk;Wv]^T  -> [4096][3072] (q:0-2047, k:2048-2559, v:2560-3071)
  k_gemm_bt<0><<<dim3(24, 32), 256, 0, stream>>>(xb, wqkv, qkvb, 2048, 2048, 2048, 3072);

  k_post<<<3072, 256, 0, stream>>>(qkvb, cosb, sinb, vTb);

  k_attn<<<dim3(32, 8), 512, 0, stream>>>(qkvb, vTb, ctx);

  k_gemm_bt<1><<<dim3(16, 32), 256, 0, stream>>>(ctx, Wob, d_out, 2048, 2048, 2048, 2048);
}

// Round 12
// 234.457 us; speedup vs baseline: 1.1575x; 1.1575x over previous
//
#include <hip/hip_runtime.h>

typedef __attribute__((ext_vector_type(8))) short bf16x8;     // 8 bf16 in 4 VGPRs
typedef __attribute__((ext_vector_type(4))) short bf16x4;     // 4 bf16 in 2 VGPRs
typedef __attribute__((ext_vector_type(8))) unsigned short u16x8;
typedef __attribute__((ext_vector_type(4))) float f32x4;

__device__ __forceinline__ unsigned short f2b(float f) {      // f32 -> bf16 RNE
  unsigned int u = __builtin_bit_cast(unsigned int, f);
  u += 0x7FFFu + ((u >> 16) & 1u);
  return (unsigned short)(u >> 16);
}
__device__ __forceinline__ float b2f(unsigned short h) {
  return __builtin_bit_cast(float, ((unsigned int)h) << 16);
}

__device__ __forceinline__ f32x4 mfma16x16x16(bf16x4 a, bf16x4 b, f32x4 c) {
#if __has_builtin(__builtin_amdgcn_mfma_f32_16x16x16bf16_1k)
  return __builtin_amdgcn_mfma_f32_16x16x16bf16_1k(a, b, c, 0, 0, 0);
#else
  asm volatile("v_mfma_f32_16x16x16_bf16 %0, %1, %2, %0" : "+v"(c) : "v"(a), "v"(b));
  return c;
#endif
}

#define AS1(p) (const __attribute__((address_space(1))) void*)(p)
#define AS3(p) (__attribute__((address_space(3))) void*)(p)

// ---------------- merged f32 -> bf16 convert (5 segments) ----------------
__device__ __forceinline__ void cvt8(const float* __restrict__ in,
                                     unsigned short* __restrict__ out,
                                     int i, float scale) {
  const float4* p = (const float4*)in + (size_t)i * 2;
  float4 a = p[0], b = p[1];
  u16x8 r;
  r[0] = f2b(a.x * scale); r[1] = f2b(a.y * scale);
  r[2] = f2b(a.z * scale); r[3] = f2b(a.w * scale);
  r[4] = f2b(b.x * scale); r[5] = f2b(b.y * scale);
  r[6] = f2b(b.z * scale); r[7] = f2b(b.w * scale);
  *((u16x8*)out + i) = r;
}

__global__ __launch_bounds__(256) void k_cvt_all(
    const float* __restrict__ x,  const float* __restrict__ Wq,
    const float* __restrict__ Wk, const float* __restrict__ Wv,
    const float* __restrict__ Wo, unsigned short* __restrict__ xb,
    unsigned short* __restrict__ wqkv, unsigned short* __restrict__ Wob,
    float sc) {
  int bid = blockIdx.x;                      // 9216 blocks total, 2048 elems each
  int tid = threadIdx.x;
  if (bid < 4096)      cvt8(x,  xb,             (bid        ) * 256 + tid, 1.f);
  else if (bid < 6144) cvt8(Wq, wqkv,           (bid - 4096) * 256 + tid, sc);
  else if (bid < 6656) cvt8(Wk, wqkv + 4194304, (bid - 6144) * 256 + tid, 1.f);
  else if (bid < 7168) cvt8(Wv, wqkv + 5242880, (bid - 6656) * 256 + tid, 1.f);
  else                 cvt8(Wo, Wob,            (bid - 7168) * 256 + tid, 1.f);
}

// ---------------- merged RoPE (q/k cols) + V transpose ----------------
__global__ __launch_bounds__(256) void k_post(unsigned short* __restrict__ qkv,
                                              const float* __restrict__ cosb,
                                              const float* __restrict__ sinb,
                                              unsigned short* __restrict__ vT) {
  __shared__ unsigned short tile[64][72];
  const int bid = blockIdx.x, t = threadIdx.x;
  if (bid < 2560) {
    int tid = bid * 256 + t;                 // 4096*20*8 = 655360
    int oct = tid & 7;
    int hd  = (tid >> 3) % 20;
    int s   = (tid >> 3) / 20;
    unsigned short* p1 = qkv + (size_t)s * 3072 + hd * 128 + oct * 8;
    unsigned short* p2 = p1 + 64;
    u16x8 a = *(const u16x8*)p1;
    u16x8 b = *(const u16x8*)p2;
    const float4* cp = (const float4*)(cosb + (size_t)s * 128 + oct * 8);
    const float4* sp = (const float4*)(sinb + (size_t)s * 128 + oct * 8);
    float4 c0 = cp[0], c1 = cp[1], s0 = sp[0], s1 = sp[1];
    float cs[8] = {c0.x,c0.y,c0.z,c0.w,c1.x,c1.y,c1.z,c1.w};
    float sn[8] = {s0.x,s0.y,s0.z,s0.w,s1.x,s1.y,s1.z,s1.w};
    u16x8 ra, rb;
#pragma unroll
    for (int j = 0; j < 8; ++j) {
      float av = b2f(a[j]), bv = b2f(b[j]);
      ra[j] = f2b(av * cs[j] - bv * sn[j]);
      rb[j] = f2b(bv * cs[j] + av * sn[j]);
    }
    *(u16x8*)p1 = ra;
    *(u16x8*)p2 = rb;
  } else {
    int idx = bid - 2560;                    // 512 tiles
    int bs = idx >> 3, bc = idx & 7;
#pragma unroll
    for (int i = 0; i < 2; ++i) {
      int c8 = t + 256 * i;                  // 0..511
      int row = c8 >> 3, cb = c8 & 7;
      u16x8 v = *(const u16x8*)(qkv + (size_t)(bs * 64 + row) * 3072 + 2560 + bc * 64 + cb * 8);
#pragma unroll
      for (int j = 0; j < 8; ++j) tile[row][cb * 8 + j] = v[j];
    }
    __syncthreads();
#pragma unroll
    for (int i = 0; i < 2; ++i) {
      int c8 = t + 256 * i;
      int crow = c8 >> 3, sb = c8 & 7;
      u16x8 v;
#pragma unroll
      for (int j = 0; j < 8; ++j) v[j] = tile[sb * 8 + j][crow];
      *(u16x8*)(vT + (size_t)(bc * 64 + crow) * 4096 + bs * 64 + sb * 8) = v;
    }
  }
}

// ---------------- GEMM C[M,N] = A[M,K] @ B[N,K]^T (bf16 in, bf16/f32 out) --
template <int OUTF32>
__global__ __launch_bounds__(256) void k_gemm_bt(
    const unsigned short* __restrict__ A, const unsigned short* __restrict__ B,
    void* __restrict__ C, int K, int lda, int ldb, int ldc) {
  __shared__ unsigned short As[128 * 64];
  __shared__ unsigned short Bs[128 * 64];
  const int t = threadIdx.x;
  const int lane = t & 63, w = t >> 6;
  const int wm = w >> 1, wn = w & 1;
  const int bn = blockIdx.x, bm = blockIdx.y;
  const unsigned short* Arow = A + (size_t)(bm * 128) * lda;
  const unsigned short* Brow = B + (size_t)(bn * 128) * ldb;

  f32x4 acc[4][4] = {};
  for (int kt = 0; kt < K; kt += 64) {
#pragma unroll
    for (int i = 0; i < 4; ++i) {
      int idx = i * 256 + t;
      int r = idx >> 3, blk = idx & 7;
      int sb = blk ^ (r & 7);
      __builtin_amdgcn_global_load_lds(AS1(Arow + (size_t)r * lda + kt + sb * 8),
                                       AS3(As + (i * 256 + w * 64) * 8), 16, 0, 0);
    }
#pragma unroll
    for (int i = 0; i < 4; ++i) {
      int idx = i * 256 + t;
      int r = idx >> 3, blk = idx & 7;
      int sb = blk ^ (r & 7);
      __builtin_amdgcn_global_load_lds(AS1(Brow + (size_t)r * ldb + kt + sb * 8),
                                       AS3(Bs + (i * 256 + w * 64) * 8), 16, 0, 0);
    }
    __syncthreads();
#pragma unroll
    for (int kk = 0; kk < 2; ++kk) {
      bf16x8 av[4], bv[4];
#pragma unroll
      for (int i = 0; i < 4; ++i) {
        int r = wm * 64 + i * 16 + (lane & 15);
        int off = (r * 128 + (kk * 32 + (lane >> 4) * 8) * 2) ^ ((r & 7) << 4);
        av[i] = *(const bf16x8*)((const char*)As + off);
      }
#pragma unroll
      for (int j = 0; j < 4; ++j) {
        int r = wn * 64 + j * 16 + (lane & 15);
        int off = (r * 128 + (kk * 32 + (lane >> 4) * 8) * 2) ^ ((r & 7) << 4);
        bv[j] = *(const bf16x8*)((const char*)Bs + off);
      }
#pragma unroll
      for (int i = 0; i < 4; ++i)
#pragma unroll
        for (int j = 0; j < 4; ++j)
          acc[i][j] = __builtin_amdgcn_mfma_f32_16x16x32_bf16(av[i], bv[j], acc[i][j], 0, 0, 0);
    }
    __syncthreads();
  }
#pragma unroll
  for (int i = 0; i < 4; ++i)
#pragma unroll
    for (int j = 0; j < 4; ++j)
#pragma unroll
      for (int r = 0; r < 4; ++r) {
        int m = bm * 128 + wm * 64 + i * 16 + (lane >> 4) * 4 + r;
        int n = bn * 128 + wn * 64 + j * 16 + (lane & 15);
        float v = acc[i][j][r];
        if (OUTF32) ((float*)C)[(size_t)m * ldc + n] = v;
        else        ((unsigned short*)C)[(size_t)m * ldc + n] = f2b(v);
      }
}

// ---------------- attention staging helpers (r4/r10-proven) ----------------
__device__ __forceinline__ void stage_k(const unsigned short* __restrict__ qk,
                                        unsigned short* __restrict__ dst,
                                        int kt, int g, int t, int w) {
#pragma unroll
  for (int i = 0; i < 4; ++i) {   // K tile [64 keys][128 d], swz low 3 bits of col16
    int idx = i * 256 + t;
    int r = idx >> 4, blk = idx & 15;
    int sb = (blk & 8) | ((blk ^ r) & 7);
    __builtin_amdgcn_global_load_lds(
        AS1(qk + (size_t)(kt * 64 + r) * 3072 + 2048 + g * 128 + sb * 8),
        AS3(dst + (i * 256 + w * 64) * 8), 16, 0, 0);
  }
}
__device__ __forceinline__ void stage_v(const unsigned short* __restrict__ vT,
                                        unsigned short* __restrict__ dst,
                                        int kt, int g, int t, int w) {
#pragma unroll
  for (int i = 0; i < 4; ++i) {   // V^T tile [128 d][64 keys]
    int idx = i * 256 + t;
    int r = idx >> 3, blk = idx & 7;
    int sb = blk ^ (r & 7);
    __builtin_amdgcn_global_load_lds(
        AS1(vT + (size_t)(g * 128 + r) * 4096 + kt * 64 + sb * 8),
        AS3(dst + (i * 256 + w * 64) * 8), 16, 0, 0);
  }
}

// ---------------- fused causal GQA flash attention (split-K in block) ------
// 512 threads: group A (waves 0-3) keys [0,m), group B (waves 4-7) keys
// [m,qt+1), m=ceil((qt+1)/2) -> EQUAL concurrent halves. Max-free softmax
// makes partials exactly summable: O=(O_A+O_B)/(l_A+l_B), combined in LDS.
// Critical path per (qt,hp) halves: ph-loop pairing (qt=b, 63-b) gives every
// block a uniform ~33 tile-iterations (vs r9's 66, r10's 64-makespan).
// Per-wave tile math identical to r10 (2 heads of one KV group per wave,
// swapped QK^T, register P, dbuf K/V per group). LDS 128KB -> 1 block/CU.
__global__ __launch_bounds__(512, 1) void k_attn(const unsigned short* __restrict__ qk,
                                                 const unsigned short* __restrict__ vT,
                                                 unsigned short* __restrict__ ctx) {
  __shared__ unsigned short Ks[2][2][64 * 128];   // [group][parity]
  __shared__ unsigned short Vs[2][2][64 * 128];
  const int b = blockIdx.x;                  // 0..31
  const int hp = blockIdx.y;                 // head pair: heads 2hp, 2hp+1
  const int h0 = hp * 2, g = hp >> 1;
  const int t = threadIdx.x;                 // 0..511
  const int grp = t >> 8;                    // 0 = keys low half, 1 = high half
  const int tg = t & 255;                    // thread within group
  const int lane = t & 63, w4 = (t >> 6) & 3;
  const int l15 = lane & 15, lq = lane >> 4;

  float* ol = (float*)&Ks[0][0][0];          // 64KB combine scratch (post-loop)
  float* ll = (float*)&Vs[0][0][0];          // lsum scratch (post-loop)

  for (int ph = 0; ph < 2; ++ph) {
    const int qt = ph ? 63 - b : b;
    const int ntot = qt + 1;
    const int m = (ntot + 1) >> 1;           // group A tiles [0,m)
    const int nB = ntot - m;                 // group B tiles [m,ntot), nB <= m
    const int kbase = grp ? m : 0;
    const int ntile = grp ? nB : m;
    const int qg = qt * 64 + w4 * 16 + l15;  // this lane's softmax q-row

    bf16x8 aq0[4], aq1[4];        // Q fragments, both heads (same rows, both groups)
    {
      const unsigned short* qb =
          qk + (size_t)(qt * 64 + w4 * 16 + l15) * 3072 + h0 * 128 + lq * 8;
#pragma unroll
      for (int sl = 0; sl < 4; ++sl) {
        aq0[sl] = *(const bf16x8*)(qb + sl * 32);
        aq1[sl] = *(const bf16x8*)(qb + 128 + sl * 32);
      }
    }
    f32x4 o0[8] = {}, o1[8] = {};
    float lsum0 = 0.f, lsum1 = 0.f;

    unsigned short* K0 = Ks[grp][0];
    unsigned short* K1 = Ks[grp][1];
    unsigned short* V0 = Vs[grp][0];
    unsigned short* V1 = Vs[grp][1];

    if (ntile > 0) {                         // prologue: stage my first tile
      stage_k(qk, K0, kbase, g, tg, w4);
      stage_v(vT, V0, kbase, g, tg, w4);
    }
    asm volatile("s_waitcnt vmcnt(0)" ::: "memory");
    __builtin_amdgcn_s_barrier();

    auto tile = [&](const unsigned short* Kb, const unsigned short* Vb,
                    int kt, bool maskT) {
      f32x4 st0[4] = {}, st1[4] = {};
      __builtin_amdgcn_s_setprio(1);
#pragma unroll
      for (int sl = 0; sl < 4; ++sl)
#pragma unroll
        for (int nt = 0; nt < 4; ++nt) {
          int key = nt * 16 + l15;
          int off = (key * 256 + sl * 64 + lq * 16) ^ ((key & 7) << 4);
          bf16x8 bk = *(const bf16x8*)((const char*)Kb + off);
          st0[nt] = __builtin_amdgcn_mfma_f32_16x16x32_bf16(bk, aq0[sl], st0[nt], 0, 0, 0);
          st1[nt] = __builtin_amdgcn_mfma_f32_16x16x32_bf16(bk, aq1[sl], st1[nt], 0, 0, 0);
        }
      __builtin_amdgcn_s_setprio(0);

      bf16x4 pa0[4], pa1[4];
#pragma unroll
      for (int nt = 0; nt < 4; ++nt)
#pragma unroll
        for (int r = 0; r < 4; ++r) {
          float p0 = __builtin_amdgcn_exp2f(st0[nt][r]);
          float p1 = __builtin_amdgcn_exp2f(st1[nt][r]);
          if (maskT) {
            int key = kt * 64 + nt * 16 + lq * 4 + r;
            if (key > qg) { p0 = 0.f; p1 = 0.f; }
          }
          lsum0 += p0; lsum1 += p1;
          unsigned int u0 = __builtin_bit_cast(unsigned int, p0) + 0x8000u;
          unsigned int u1 = __builtin_bit_cast(unsigned int, p1) + 0x8000u;
          pa0[nt][r] = (short)(u0 >> 16);
          pa1[nt][r] = (short)(u1 >> 16);
        }

      __builtin_amdgcn_s_setprio(1);
#pragma unroll
      for (int nt = 0; nt < 4; ++nt)
#pragma unroll
        for (int dt = 0; dt < 8; ++dt) {
          int d = dt * 16 + l15;
          int off = (d * 128 + nt * 32 + lq * 8) ^ ((d & 7) << 4);
          bf16x4 vv = *(const bf16x4*)((const char*)Vb + off);
          o0[dt] = mfma16x16x16(pa0[nt], vv, o0[dt]);
          o1[dt] = mfma16x16x16(pa1[nt], vv, o1[dt]);
        }
      __builtin_amdgcn_s_setprio(0);
    };

    for (int i = 0; i < m; ++i) {            // both groups run m iterations
      const int cur = i & 1;
      if (i + 1 < ntile) {                   // prefetch my next tile
        stage_k(qk, cur ? K0 : K1, kbase + i + 1, g, tg, w4);
        stage_v(vT, cur ? V0 : V1, kbase + i + 1, g, tg, w4);
      }
      if (i < ntile) {
        const int kt = kbase + i;
        tile(cur ? K1 : K0, cur ? V1 : V0, kt, kt == qt);
      }
      asm volatile("s_waitcnt vmcnt(0)" ::: "memory");
      __builtin_amdgcn_s_barrier();          // also fences K/V reads for reuse
    }

    // ---- combine: O = (O_A + O_B) / (l_A + l_B) via LDS ----
    float f0 = lsum0, f1 = lsum1;            // reduce partial row sums
    f0 += __shfl_xor(f0, 16); f0 += __shfl_xor(f0, 32);
    f1 += __shfl_xor(f1, 16); f1 += __shfl_xor(f1, 32);

    if (grp == 1) {                          // B publishes partials
#pragma unroll
      for (int dt = 0; dt < 8; ++dt)
#pragma unroll
        for (int r = 0; r < 4; ++r) {
          ol[(dt * 4 + r) * 256 + tg]        = o0[dt][r];
          ol[(32 + dt * 4 + r) * 256 + tg]   = o1[dt][r];
        }
      if (lq == 0) {
        ll[w4 * 16 + l15]      = f0;
        ll[64 + w4 * 16 + l15] = f1;
      }
    }
    __builtin_amdgcn_s_barrier();
    if (grp == 0) {                          // A combines, normalizes, stores
#pragma unroll
      for (int dt = 0; dt < 8; ++dt)
#pragma unroll
        for (int r = 0; r < 4; ++r) {
          o0[dt][r] += ol[(dt * 4 + r) * 256 + tg];
          o1[dt][r] += ol[(32 + dt * 4 + r) * 256 + tg];
        }
      f0 += ll[w4 * 16 + l15];
      f1 += ll[64 + w4 * 16 + l15];
      float iq0[4], iq1[4];
#pragma unroll
      for (int r = 0; r < 4; ++r) {
        iq0[r] = 1.f / __shfl(f0, lq * 4 + r);
        iq1[r] = 1.f / __shfl(f1, lq * 4 + r);
      }
#pragma unroll
      for (int dt = 0; dt < 8; ++dt)
#pragma unroll
        for (int r = 0; r < 4; ++r) {
          int q = qt * 64 + w4 * 16 + lq * 4 + r;
          int c = h0 * 128 + dt * 16 + l15;
          ctx[(size_t)q * 2048 + c]       = f2b(o0[dt][r] * iq0[r]);
          ctx[(size_t)q * 2048 + c + 128] = f2b(o1[dt][r] * iq1[r]);
        }
    }
    __builtin_amdgcn_s_barrier();            // protect LDS for next phase
  }
}

// ---------------- host ----------------
extern "C" void kernel_launch(void* const* d_in, const int* in_sizes, int n_in,
                              void* d_out, int out_size, void* d_ws, size_t ws_size,
                              hipStream_t stream) {
  const float* x    = (const float*)d_in[0];
  const float* cosb = (const float*)d_in[2];
  const float* sinb = (const float*)d_in[3];
  const float* Wq   = (const float*)d_in[4];
  const float* Wk   = (const float*)d_in[5];
  const float* Wv   = (const float*)d_in[6];
  const float* Wo   = (const float*)d_in[7];

  char* p = (char*)d_ws;
  unsigned short* xb   = (unsigned short*)p; p += (size_t)8388608 * 2;   // x bf16
  unsigned short* wqkv = (unsigned short*)p; p += (size_t)6291456 * 2;   // [3072][2048]
  unsigned short* Wob  = (unsigned short*)p; p += (size_t)4194304 * 2;
  unsigned short* qkvb = (unsigned short*)p; p += (size_t)4096 * 3072 * 2;
  unsigned short* vTb  = (unsigned short*)p; p += (size_t)512 * 4096 * 2;
  unsigned short* ctx  = (unsigned short*)p; p += (size_t)4096 * 2048 * 2;
  if (ws_size < (size_t)(p - (char*)d_ws)) return;

  const float SC = 0.12751741f;   // (1/sqrt(128)) * log2(e), folded into Wq

  k_cvt_all<<<9216, 256, 0, stream>>>(x, Wq, Wk, Wv, Wo, xb, wqkv, Wob, SC);

  // qkv = x @ [Wq;Wk;Wv]^T  -> [4096][3072] (q:0-2047, k:2048-2559, v:2560-3071)
  k_gemm_bt<0><<<dim3(24, 32), 256, 0, stream>>>(xb, wqkv, qkvb, 2048, 2048, 2048, 3072);

  k_post<<<3072, 256, 0, stream>>>(qkvb, cosb, sinb, vTb);

  k_attn<<<dim3(32, 8), 512, 0, stream>>>(qkvb, vTb, ctx);

  k_gemm_bt<1><<<dim3(16, 32), 256, 0, stream>>>(ctx, Wob, d_out, 2048, 2048, 2048, 2048);
}

// Round 13
// 233.846 us; speedup vs baseline: 1.1605x; 1.0026x over previous
//
#include <hip/hip_runtime.h>

typedef __attribute__((ext_vector_type(8))) short bf16x8;     // 8 bf16 in 4 VGPRs
typedef __attribute__((ext_vector_type(4))) short bf16x4;     // 4 bf16 in 2 VGPRs
typedef __attribute__((ext_vector_type(8))) unsigned short u16x8;
typedef __attribute__((ext_vector_type(4))) float f32x4;

__device__ __forceinline__ unsigned short f2b(float f) {      // f32 -> bf16 RNE
  unsigned int u = __builtin_bit_cast(unsigned int, f);
  u += 0x7FFFu + ((u >> 16) & 1u);
  return (unsigned short)(u >> 16);
}
__device__ __forceinline__ float b2f(unsigned short h) {
  return __builtin_bit_cast(float, ((unsigned int)h) << 16);
}

__device__ __forceinline__ f32x4 mfma16x16x16(bf16x4 a, bf16x4 b, f32x4 c) {
#if __has_builtin(__builtin_amdgcn_mfma_f32_16x16x16bf16_1k)
  return __builtin_amdgcn_mfma_f32_16x16x16bf16_1k(a, b, c, 0, 0, 0);
#else
  asm volatile("v_mfma_f32_16x16x16_bf16 %0, %1, %2, %0" : "+v"(c) : "v"(a), "v"(b));
  return c;
#endif
}

#define AS1(p) (const __attribute__((address_space(1))) void*)(p)
#define AS3(p) (__attribute__((address_space(3))) void*)(p)

// ---------------- merged f32 -> bf16 convert (5 segments) ----------------
__device__ __forceinline__ void cvt8(const float* __restrict__ in,
                                     unsigned short* __restrict__ out,
                                     int i, float scale) {
  const float4* p = (const float4*)in + (size_t)i * 2;
  float4 a = p[0], b = p[1];
  u16x8 r;
  r[0] = f2b(a.x * scale); r[1] = f2b(a.y * scale);
  r[2] = f2b(a.z * scale); r[3] = f2b(a.w * scale);
  r[4] = f2b(b.x * scale); r[5] = f2b(b.y * scale);
  r[6] = f2b(b.z * scale); r[7] = f2b(b.w * scale);
  *((u16x8*)out + i) = r;
}

__global__ __launch_bounds__(256) void k_cvt_all(
    const float* __restrict__ x,  const float* __restrict__ Wq,
    const float* __restrict__ Wk, const float* __restrict__ Wv,
    const float* __restrict__ Wo, unsigned short* __restrict__ xb,
    unsigned short* __restrict__ wqkv, unsigned short* __restrict__ Wob,
    float sc) {
  int bid = blockIdx.x;                      // 9216 blocks total, 2048 elems each
  int tid = threadIdx.x;
  if (bid < 4096)      cvt8(x,  xb,             (bid        ) * 256 + tid, 1.f);
  else if (bid < 6144) cvt8(Wq, wqkv,           (bid - 4096) * 256 + tid, sc);
  else if (bid < 6656) cvt8(Wk, wqkv + 4194304, (bid - 6144) * 256 + tid, 1.f);
  else if (bid < 7168) cvt8(Wv, wqkv + 5242880, (bid - 6656) * 256 + tid, 1.f);
  else                 cvt8(Wo, Wob,            (bid - 7168) * 256 + tid, 1.f);
}

// ---------------- merged RoPE (q/k cols) + V transpose ----------------
__global__ __launch_bounds__(256) void k_post(unsigned short* __restrict__ qkv,
                                              const float* __restrict__ cosb,
                                              const float* __restrict__ sinb,
                                              unsigned short* __restrict__ vT) {
  __shared__ unsigned short tile[64][72];
  const int bid = blockIdx.x, t = threadIdx.x;
  if (bid < 2560) {
    int tid = bid * 256 + t;                 // 4096*20*8 = 655360
    int oct = tid & 7;
    int hd  = (tid >> 3) % 20;
    int s   = (tid >> 3) / 20;
    unsigned short* p1 = qkv + (size_t)s * 3072 + hd * 128 + oct * 8;
    unsigned short* p2 = p1 + 64;
    u16x8 a = *(const u16x8*)p1;
    u16x8 b = *(const u16x8*)p2;
    const float4* cp = (const float4*)(cosb + (size_t)s * 128 + oct * 8);
    const float4* sp = (const float4*)(sinb + (size_t)s * 128 + oct * 8);
    float4 c0 = cp[0], c1 = cp[1], s0 = sp[0], s1 = sp[1];
    float cs[8] = {c0.x,c0.y,c0.z,c0.w,c1.x,c1.y,c1.z,c1.w};
    float sn[8] = {s0.x,s0.y,s0.z,s0.w,s1.x,s1.y,s1.z,s1.w};
    u16x8 ra, rb;
#pragma unroll
    for (int j = 0; j < 8; ++j) {
      float av = b2f(a[j]), bv = b2f(b[j]);
      ra[j] = f2b(av * cs[j] - bv * sn[j]);
      rb[j] = f2b(bv * cs[j] + av * sn[j]);
    }
    *(u16x8*)p1 = ra;
    *(u16x8*)p2 = rb;
  } else {
    int idx = bid - 2560;                    // 512 tiles
    int bs = idx >> 3, bc = idx & 7;
#pragma unroll
    for (int i = 0; i < 2; ++i) {
      int c8 = t + 256 * i;                  // 0..511
      int row = c8 >> 3, cb = c8 & 7;
      u16x8 v = *(const u16x8*)(qkv + (size_t)(bs * 64 + row) * 3072 + 2560 + bc * 64 + cb * 8);
#pragma unroll
      for (int j = 0; j < 8; ++j) tile[row][cb * 8 + j] = v[j];
    }
    __syncthreads();
#pragma unroll
    for (int i = 0; i < 2; ++i) {
      int c8 = t + 256 * i;
      int crow = c8 >> 3, sb = c8 & 7;
      u16x8 v;
#pragma unroll
      for (int j = 0; j < 8; ++j) v[j] = tile[sb * 8 + j][crow];
      *(u16x8*)(vT + (size_t)(bc * 64 + crow) * 4096 + bs * 64 + sb * 8) = v;
    }
  }
}

// ---------------- GEMM C[M,N] = A[M,K] @ B[N,K]^T (bf16 in, bf16/f32 out) --
// XCD-swizzled block mapping: same-bn blocks (sharing a 512KB B-panel)
// cluster onto one XCD's L2. Requires gridDim.x % 8 == 0 (bijective).
template <int OUTF32>
__global__ __launch_bounds__(256) void k_gemm_bt(
    const unsigned short* __restrict__ A, const unsigned short* __restrict__ B,
    void* __restrict__ C, int K, int lda, int ldb, int ldc) {
  __shared__ unsigned short As[128 * 64];
  __shared__ unsigned short Bs[128 * 64];
  const int t = threadIdx.x;
  const int lane = t & 63, w = t >> 6;
  const int wm = w >> 1, wn = w & 1;
  // XCD swizzle: dispatch-linear id o -> XCD x = o&7 gets bn in [x*per, x*per+per)
  const int o = blockIdx.x + blockIdx.y * gridDim.x;
  const int xcd = o & 7, j = o >> 3;
  const int per = gridDim.x >> 3;            // bn-panels per XCD
  const int bn = xcd * per + (j % per);
  const int bm = j / per;
  const unsigned short* Arow = A + (size_t)(bm * 128) * lda;
  const unsigned short* Brow = B + (size_t)(bn * 128) * ldb;

  f32x4 acc[4][4] = {};
  for (int kt = 0; kt < K; kt += 64) {
#pragma unroll
    for (int i = 0; i < 4; ++i) {
      int idx = i * 256 + t;
      int r = idx >> 3, blk = idx & 7;
      int sb = blk ^ (r & 7);
      __builtin_amdgcn_global_load_lds(AS1(Arow + (size_t)r * lda + kt + sb * 8),
                                       AS3(As + (i * 256 + w * 64) * 8), 16, 0, 0);
    }
#pragma unroll
    for (int i = 0; i < 4; ++i) {
      int idx = i * 256 + t;
      int r = idx >> 3, blk = idx & 7;
      int sb = blk ^ (r & 7);
      __builtin_amdgcn_global_load_lds(AS1(Brow + (size_t)r * ldb + kt + sb * 8),
                                       AS3(Bs + (i * 256 + w * 64) * 8), 16, 0, 0);
    }
    __syncthreads();
#pragma unroll
    for (int kk = 0; kk < 2; ++kk) {
      bf16x8 av[4], bv[4];
#pragma unroll
      for (int i = 0; i < 4; ++i) {
        int r = wm * 64 + i * 16 + (lane & 15);
        int off = (r * 128 + (kk * 32 + (lane >> 4) * 8) * 2) ^ ((r & 7) << 4);
        av[i] = *(const bf16x8*)((const char*)As + off);
      }
#pragma unroll
      for (int j2 = 0; j2 < 4; ++j2) {
        int r = wn * 64 + j2 * 16 + (lane & 15);
        int off = (r * 128 + (kk * 32 + (lane >> 4) * 8) * 2) ^ ((r & 7) << 4);
        bv[j2] = *(const bf16x8*)((const char*)Bs + off);
      }
#pragma unroll
      for (int i = 0; i < 4; ++i)
#pragma unroll
        for (int j2 = 0; j2 < 4; ++j2)
          acc[i][j2] = __builtin_amdgcn_mfma_f32_16x16x32_bf16(av[i], bv[j2], acc[i][j2], 0, 0, 0);
    }
    __syncthreads();
  }
#pragma unroll
  for (int i = 0; i < 4; ++i)
#pragma unroll
    for (int j2 = 0; j2 < 4; ++j2)
#pragma unroll
      for (int r = 0; r < 4; ++r) {
        int m = bm * 128 + wm * 64 + i * 16 + (lane >> 4) * 4 + r;
        int n = bn * 128 + wn * 64 + j2 * 16 + (lane & 15);
        float v = acc[i][j2][r];
        if (OUTF32) ((float*)C)[(size_t)m * ldc + n] = v;
        else        ((unsigned short*)C)[(size_t)m * ldc + n] = f2b(v);
      }
}

// ---------------- attention staging helpers (r4/r10-proven) ----------------
__device__ __forceinline__ void stage_k(const unsigned short* __restrict__ qk,
                                        unsigned short* __restrict__ dst,
                                        int kt, int g, int t, int w) {
#pragma unroll
  for (int i = 0; i < 4; ++i) {   // K tile [64 keys][128 d], swz low 3 bits of col16
    int idx = i * 256 + t;
    int r = idx >> 4, blk = idx & 15;
    int sb = (blk & 8) | ((blk ^ r) & 7);
    __builtin_amdgcn_global_load_lds(
        AS1(qk + (size_t)(kt * 64 + r) * 3072 + 2048 + g * 128 + sb * 8),
        AS3(dst + (i * 256 + w * 64) * 8), 16, 0, 0);
  }
}
__device__ __forceinline__ void stage_v(const unsigned short* __restrict__ vT,
                                        unsigned short* __restrict__ dst,
                                        int kt, int g, int t, int w) {
#pragma unroll
  for (int i = 0; i < 4; ++i) {   // V^T tile [128 d][64 keys]
    int idx = i * 256 + t;
    int r = idx >> 3, blk = idx & 7;
    int sb = blk ^ (r & 7);
    __builtin_amdgcn_global_load_lds(
        AS1(vT + (size_t)(g * 128 + r) * 4096 + kt * 64 + sb * 8),
        AS3(dst + (i * 256 + w * 64) * 8), 16, 0, 0);
  }
}

// ---------------- fused causal GQA flash attention (split-K in block) ------
// r12 structure unchanged. Grid flattened to 1D with hp = bid & 7 so all 32
// blocks of one head-pair (sharing the same 4MB K+V working set) land on one
// XCD's L2 under round-robin dispatch (was: striped across 8 XCDs, FETCH 2.4x
// the unique bytes).
__global__ __launch_bounds__(512, 1) void k_attn(const unsigned short* __restrict__ qk,
                                                 const unsigned short* __restrict__ vT,
                                                 unsigned short* __restrict__ ctx) {
  __shared__ unsigned short Ks[2][2][64 * 128];   // [group][parity]
  __shared__ unsigned short Vs[2][2][64 * 128];
  const int b = blockIdx.x >> 3;             // 0..31
  const int hp = blockIdx.x & 7;             // head pair: heads 2hp, 2hp+1
  const int h0 = hp * 2, g = hp >> 1;
  const int t = threadIdx.x;                 // 0..511
  const int grp = t >> 8;                    // 0 = keys low half, 1 = high half
  const int tg = t & 255;                    // thread within group
  const int lane = t & 63, w4 = (t >> 6) & 3;
  const int l15 = lane & 15, lq = lane >> 4;

  float* ol = (float*)&Ks[0][0][0];          // 64KB combine scratch (post-loop)
  float* ll = (float*)&Vs[0][0][0];          // lsum scratch (post-loop)

  for (int ph = 0; ph < 2; ++ph) {
    const int qt = ph ? 63 - b : b;
    const int ntot = qt + 1;
    const int m = (ntot + 1) >> 1;           // group A tiles [0,m)
    const int nB = ntot - m;                 // group B tiles [m,ntot), nB <= m
    const int kbase = grp ? m : 0;
    const int ntile = grp ? nB : m;
    const int qg = qt * 64 + w4 * 16 + l15;  // this lane's softmax q-row

    bf16x8 aq0[4], aq1[4];        // Q fragments, both heads (same rows, both groups)
    {
      const unsigned short* qb =
          qk + (size_t)(qt * 64 + w4 * 16 + l15) * 3072 + h0 * 128 + lq * 8;
#pragma unroll
      for (int sl = 0; sl < 4; ++sl) {
        aq0[sl] = *(const bf16x8*)(qb + sl * 32);
        aq1[sl] = *(const bf16x8*)(qb + 128 + sl * 32);
      }
    }
    f32x4 o0[8] = {}, o1[8] = {};
    float lsum0 = 0.f, lsum1 = 0.f;

    unsigned short* K0 = Ks[grp][0];
    unsigned short* K1 = Ks[grp][1];
    unsigned short* V0 = Vs[grp][0];
    unsigned short* V1 = Vs[grp][1];

    if (ntile > 0) {                         // prologue: stage my first tile
      stage_k(qk, K0, kbase, g, tg, w4);
      stage_v(vT, V0, kbase, g, tg, w4);
    }
    asm volatile("s_waitcnt vmcnt(0)" ::: "memory");
    __builtin_amdgcn_s_barrier();

    auto tile = [&](const unsigned short* Kb, const unsigned short* Vb,
                    int kt, bool maskT) {
      f32x4 st0[4] = {}, st1[4] = {};
      __builtin_amdgcn_s_setprio(1);
#pragma unroll
      for (int sl = 0; sl < 4; ++sl)
#pragma unroll
        for (int nt = 0; nt < 4; ++nt) {
          int key = nt * 16 + l15;
          int off = (key * 256 + sl * 64 + lq * 16) ^ ((key & 7) << 4);
          bf16x8 bk = *(const bf16x8*)((const char*)Kb + off);
          st0[nt] = __builtin_amdgcn_mfma_f32_16x16x32_bf16(bk, aq0[sl], st0[nt], 0, 0, 0);
          st1[nt] = __builtin_amdgcn_mfma_f32_16x16x32_bf16(bk, aq1[sl], st1[nt], 0, 0, 0);
        }
      __builtin_amdgcn_s_setprio(0);

      bf16x4 pa0[4], pa1[4];
#pragma unroll
      for (int nt = 0; nt < 4; ++nt)
#pragma unroll
        for (int r = 0; r < 4; ++r) {
          float p0 = __builtin_amdgcn_exp2f(st0[nt][r]);
          float p1 = __builtin_amdgcn_exp2f(st1[nt][r]);
          if (maskT) {
            int key = kt * 64 + nt * 16 + lq * 4 + r;
            if (key > qg) { p0 = 0.f; p1 = 0.f; }
          }
          lsum0 += p0; lsum1 += p1;
          unsigned int u0 = __builtin_bit_cast(unsigned int, p0) + 0x8000u;
          unsigned int u1 = __builtin_bit_cast(unsigned int, p1) + 0x8000u;
          pa0[nt][r] = (short)(u0 >> 16);
          pa1[nt][r] = (short)(u1 >> 16);
        }

      __builtin_amdgcn_s_setprio(1);
#pragma unroll
      for (int nt = 0; nt < 4; ++nt)
#pragma unroll
        for (int dt = 0; dt < 8; ++dt) {
          int d = dt * 16 + l15;
          int off = (d * 128 + nt * 32 + lq * 8) ^ ((d & 7) << 4);
          bf16x4 vv = *(const bf16x4*)((const char*)Vb + off);
          o0[dt] = mfma16x16x16(pa0[nt], vv, o0[dt]);
          o1[dt] = mfma16x16x16(pa1[nt], vv, o1[dt]);
        }
      __builtin_amdgcn_s_setprio(0);
    };

    for (int i = 0; i < m; ++i) {            // both groups run m iterations
      const int cur = i & 1;
      if (i + 1 < ntile) {                   // prefetch my next tile
        stage_k(qk, cur ? K0 : K1, kbase + i + 1, g, tg, w4);
        stage_v(vT, cur ? V0 : V1, kbase + i + 1, g, tg, w4);
      }
      if (i < ntile) {
        const int kt = kbase + i;
        tile(cur ? K1 : K0, cur ? V1 : V0, kt, kt == qt);
      }
      asm volatile("s_waitcnt vmcnt(0)" ::: "memory");
      __builtin_amdgcn_s_barrier();          // also fences K/V reads for reuse
    }

    // ---- combine: O = (O_A + O_B) / (l_A + l_B) via LDS ----
    float f0 = lsum0, f1 = lsum1;            // reduce partial row sums
    f0 += __shfl_xor(f0, 16); f0 += __shfl_xor(f0, 32);
    f1 += __shfl_xor(f1, 16); f1 += __shfl_xor(f1, 32);

    if (grp == 1) {                          // B publishes partials
#pragma unroll
      for (int dt = 0; dt < 8; ++dt)
#pragma unroll
        for (int r = 0; r < 4; ++r) {
          ol[(dt * 4 + r) * 256 + tg]        = o0[dt][r];
          ol[(32 + dt * 4 + r) * 256 + tg]   = o1[dt][r];
        }
      if (lq == 0) {
        ll[w4 * 16 + l15]      = f0;
        ll[64 + w4 * 16 + l15] = f1;
      }
    }
    __builtin_amdgcn_s_barrier();
    if (grp == 0) {                          // A combines, normalizes, stores
#pragma unroll
      for (int dt = 0; dt < 8; ++dt)
#pragma unroll
        for (int r = 0; r < 4; ++r) {
          o0[dt][r] += ol[(dt * 4 + r) * 256 + tg];
          o1[dt][r] += ol[(32 + dt * 4 + r) * 256 + tg];
        }
      f0 += ll[w4 * 16 + l15];
      f1 += ll[64 + w4 * 16 + l15];
      float iq0[4], iq1[4];
#pragma unroll
      for (int r = 0; r < 4; ++r) {
        iq0[r] = 1.f / __shfl(f0, lq * 4 + r);
        iq1[r] = 1.f / __shfl(f1, lq * 4 + r);
      }
#pragma unroll
      for (int dt = 0; dt < 8; ++dt)
#pragma unroll
        for (int r = 0; r < 4; ++r) {
          int q = qt * 64 + w4 * 16 + lq * 4 + r;
          int c = h0 * 128 + dt * 16 + l15;
          ctx[(size_t)q * 2048 + c]       = f2b(o0[dt][r] * iq0[r]);
          ctx[(size_t)q * 2048 + c + 128] = f2b(o1[dt][r] * iq1[r]);
        }
    }
    __builtin_amdgcn_s_barrier();            // protect LDS for next phase
  }
}

// ---------------- host ----------------
extern "C" void kernel_launch(void* const* d_in, const int* in_sizes, int n_in,
                              void* d_out, int out_size, void* d_ws, size_t ws_size,
                              hipStream_t stream) {
  const float* x    = (const float*)d_in[0];
  const float* cosb = (const float*)d_in[2];
  const float* sinb = (const float*)d_in[3];
  const float* Wq   = (const float*)d_in[4];
  const float* Wk   = (const float*)d_in[5];
  const float* Wv   = (const float*)d_in[6];
  const float* Wo   = (const float*)d_in[7];

  char* p = (char*)d_ws;
  unsigned short* xb   = (unsigned short*)p; p += (size_t)8388608 * 2;   // x bf16
  unsigned short* wqkv = (unsigned short*)p; p += (size_t)6291456 * 2;   // [3072][2048]
  unsigned short* Wob  = (unsigned short*)p; p += (size_t)4194304 * 2;
  unsigned short* qkvb = (unsigned short*)p; p += (size_t)4096 * 3072 * 2;
  unsigned short* vTb  = (unsigned short*)p; p += (size_t)512 * 4096 * 2;
  unsigned short* ctx  = (unsigned short*)p; p += (size_t)4096 * 2048 * 2;
  if (ws_size < (size_t)(p - (char*)d_ws)) return;

  const float SC = 0.12751741f;   // (1/sqrt(128)) * log2(e), folded into Wq

  k_cvt_all<<<9216, 256, 0, stream>>>(x, Wq, Wk, Wv, Wo, xb, wqkv, Wob, SC);

  // qkv = x @ [Wq;Wk;Wv]^T  -> [4096][3072] (q:0-2047, k:2048-2559, v:2560-3071)
  k_gemm_bt<0><<<dim3(24, 32), 256, 0, stream>>>(xb, wqkv, qkvb, 2048, 2048, 2048, 3072);

  k_post<<<3072, 256, 0, stream>>>(qkvb, cosb, sinb, vTb);

  k_attn<<<256, 512, 0, stream>>>(qkvb, vTb, ctx);

  k_gemm_bt<1><<<dim3(16, 32), 256, 0, stream>>>(ctx, Wob, d_out, 2048, 2048, 2048, 2048);
}